// Round 2
// 112.315 us; speedup vs baseline: 1.0637x; 1.0637x over previous
//
#include <hip/hip_runtime.h>
#include <hip/hip_bf16.h>
#include <hip/hip_fp16.h>

#define EPS 1e-12f
// Table stores en * 16 in fp8 e4m3 (OCP, HW cvt on gfx950); epilogue divides by 256.
#define TBL_SCALE 16.0f
#define TBL_SCALE_INV2 (1.0f / 256.0f)

typedef __attribute__((ext_vector_type(2))) float float2v;
typedef __attribute__((ext_vector_type(4))) float float4v;

// ---------- Path A: fp8 e4m3 normalized table (x16) in d_ws ----------

// One row per 32-lane half-wave: lane handles 4 elements (float4 load),
// 5-step shfl reduce for the norm, pack 4 fp8 -> one uint store per lane
// (32 lanes x 4B = 128B/row coalesced).
__global__ __launch_bounds__(256) void normalize_fp8_kernel(
    const float* __restrict__ emb, unsigned int* __restrict__ en, int N) {
    int gid  = blockIdx.x * blockDim.x + threadIdx.x;
    int row  = gid >> 5;
    int sl   = threadIdx.x & 31;
    if (row >= N) return;

    float4 v = ((const float4*)(emb + (size_t)row * 128))[sl];
    float s = v.x * v.x + v.y * v.y + v.z * v.z + v.w * v.w;
    #pragma unroll
    for (int off = 16; off; off >>= 1) s += __shfl_xor(s, off, 64);
    float inv = TBL_SCALE / fmaxf(sqrtf(s), EPS);

    int p = 0;
    p = __builtin_amdgcn_cvt_pk_fp8_f32(v.x * inv, v.y * inv, p, false);
    p = __builtin_amdgcn_cvt_pk_fp8_f32(v.z * inv, v.w * inv, p, true);
    en[(size_t)row * 32 + sl] = (unsigned int)p;
}

// 16 fp8 x 16 fp8 dot with per-element d weights (dd uniform per sub-lane).
__device__ __forceinline__ float dot_fp8_16(uint4 a, uint4 b, const float* dd) {
    const unsigned int* aw = (const unsigned int*)&a;
    const unsigned int* bw = (const unsigned int*)&b;
    float p = 0.0f;
    #pragma unroll
    for (int w = 0; w < 4; ++w) {
        float2v a0 = __builtin_amdgcn_cvt_pk_f32_fp8((int)aw[w], false);
        float2v a1 = __builtin_amdgcn_cvt_pk_f32_fp8((int)aw[w], true);
        float2v b0 = __builtin_amdgcn_cvt_pk_f32_fp8((int)bw[w], false);
        float2v b1 = __builtin_amdgcn_cvt_pk_f32_fp8((int)bw[w], true);
        p += a0.x * b0.x * dd[4 * w + 0];
        p += a0.y * b0.y * dd[4 * w + 1];
        p += a1.x * b1.x * dd[4 * w + 2];
        p += a1.y * b1.y * dd[4 * w + 3];
    }
    return p;
}

// v2: FOUR edges per 8-lane group. One same-address int4 load per group for
// src/dst (indices land in-register, no shfl), then all 8 row gathers issued
// back-to-back (256 B/lane in flight = 4x MLP vs v1), one float4 nontemporal
// store per group. Lane sl covers fp8 elements [sl*16, sl*16+16) of each row.
__global__ __launch_bounds__(256) void edge_dot_fp8_v2_kernel(
    const unsigned int* __restrict__ en,
    const int* __restrict__ src, const int* __restrict__ dst,
    const float* __restrict__ d, const float* __restrict__ scale,
    float* __restrict__ out, int E) {
    int gid = blockIdx.x * blockDim.x + threadIdx.x;
    int sl  = threadIdx.x & 7;         // sub-lane in 8-lane group
    int e0  = (gid >> 3) << 2;         // 4 consecutive edges per group
    if (e0 >= E) return;

    // d fragment: elements [sl*16, sl*16+16), uniform per lane
    float dd[16];
    {
        const float4* dp = (const float4*)d;
        #pragma unroll
        for (int i = 0; i < 4; ++i) {
            float4 t = dp[sl * 4 + i];
            dd[4 * i + 0] = t.x; dd[4 * i + 1] = t.y;
            dd[4 * i + 2] = t.z; dd[4 * i + 3] = t.w;
        }
    }

    bool full = (e0 + 4 <= E);
    int si0, si1, si2, si3, di0, di1, di2, di3;
    if (full) {
        // all 8 lanes of the group load the same 16B -> 1 line, broadcast
        int4 s4 = *(const int4*)(src + e0);
        int4 t4 = *(const int4*)(dst + e0);
        si0 = s4.x; si1 = s4.y; si2 = s4.z; si3 = s4.w;
        di0 = t4.x; di1 = t4.y; di2 = t4.z; di3 = t4.w;
    } else {
        si0 = src[e0];                   di0 = dst[e0];
        si1 = (e0 + 1 < E) ? src[e0 + 1] : si0;
        di1 = (e0 + 1 < E) ? dst[e0 + 1] : di0;
        si2 = (e0 + 2 < E) ? src[e0 + 2] : si0;
        di2 = (e0 + 2 < E) ? dst[e0 + 2] : di0;
        si3 = (e0 + 3 < E) ? src[e0 + 3] : si0;
        di3 = (e0 + 3 < E) ? dst[e0 + 3] : di0;
    }

    // 8 independent 16B gathers in flight per lane (row = 8 uint4 = 128B)
    const uint4* enp = (const uint4*)en;
    uint4 a0 = enp[(size_t)si0 * 8 + sl];
    uint4 b0 = enp[(size_t)di0 * 8 + sl];
    uint4 a1 = enp[(size_t)si1 * 8 + sl];
    uint4 b1 = enp[(size_t)di1 * 8 + sl];
    uint4 a2 = enp[(size_t)si2 * 8 + sl];
    uint4 b2 = enp[(size_t)di2 * 8 + sl];
    uint4 a3 = enp[(size_t)si3 * 8 + sl];
    uint4 b3 = enp[(size_t)di3 * 8 + sl];

    float p0 = dot_fp8_16(a0, b0, dd);
    float p1 = dot_fp8_16(a1, b1, dd);
    float p2 = dot_fp8_16(a2, b2, dd);
    float p3 = dot_fp8_16(a3, b3, dd);

    // reduce across the 8-lane group (xor masks < 8 stay in-group)
    #pragma unroll
    for (int off = 4; off; off >>= 1) {
        p0 += __shfl_xor(p0, off, 64);
        p1 += __shfl_xor(p1, off, 64);
        p2 += __shfl_xor(p2, off, 64);
        p3 += __shfl_xor(p3, off, 64);
    }

    if (sl == 0) {
        float sc = scale[0] * TBL_SCALE_INV2;
        if (full) {
            float4v r = {p0 * sc, p1 * sc, p2 * sc, p3 * sc};
            __builtin_nontemporal_store(r, (float4v*)(out + e0));
        } else {
            out[e0] = p0 * sc;
            if (e0 + 1 < E) out[e0 + 1] = p1 * sc;
            if (e0 + 2 < E) out[e0 + 2] = p2 * sc;
            if (e0 + 3 < E) out[e0 + 3] = p3 * sc;
        }
    }
}

// ---------- Path B (fallback, ws too small): fp16 table (round-2) ----------

__global__ __launch_bounds__(256) void normalize_fp16_kernel(
    const float* __restrict__ emb, __half* __restrict__ en, int N) {
    int gid  = blockIdx.x * blockDim.x + threadIdx.x;
    int row  = gid >> 6;
    int lane = threadIdx.x & 63;
    if (row >= N) return;
    const float2* r = (const float2*)(emb + (size_t)row * 128);
    float2 v = r[lane];
    float s = v.x * v.x + v.y * v.y;
    #pragma unroll
    for (int off = 32; off; off >>= 1) s += __shfl_xor(s, off, 64);
    float inv = 1.0f / fmaxf(sqrtf(s), EPS);
    __half2* w = (__half2*)(en + (size_t)row * 128);
    w[lane] = __float22half2_rn(make_float2(v.x * inv, v.y * inv));
}

__global__ __launch_bounds__(256) void edge_dot_fp16_kernel(
    const __half* __restrict__ en,
    const int* __restrict__ src, const int* __restrict__ dst,
    const float* __restrict__ d, const float* __restrict__ scale,
    float* __restrict__ out, int E) {
    int gid  = blockIdx.x * blockDim.x + threadIdx.x;
    int lane = threadIdx.x & 63;
    int sub  = lane >> 4;
    int sl   = lane & 15;
    int e    = ((gid >> 6) << 2) + sub;
    float4 d0 = ((const float4*)d)[sl * 2];
    float4 d1 = ((const float4*)d)[sl * 2 + 1];
    float dd[8] = {d0.x, d0.y, d0.z, d0.w, d1.x, d1.y, d1.z, d1.w};
    float p = 0.0f;
    if (e < E) {
        int si = src[e];
        int di = dst[e];
        float4 a = ((const float4*)(en + (size_t)si * 128))[sl];
        float4 b = ((const float4*)(en + (size_t)di * 128))[sl];
        const __half2* ah = (const __half2*)&a;
        const __half2* bh = (const __half2*)&b;
        #pragma unroll
        for (int i = 0; i < 4; ++i) {
            float2 af = __half22float2(ah[i]);
            float2 bf = __half22float2(bh[i]);
            p += af.x * bf.x * dd[2 * i];
            p += af.y * bf.y * dd[2 * i + 1];
        }
    }
    #pragma unroll
    for (int off = 8; off; off >>= 1) p += __shfl_xor(p, off, 64);
    if (sl == 0 && e < E) out[e] = p * scale[0];
}

extern "C" void kernel_launch(void* const* d_in, const int* in_sizes, int n_in,
                              void* d_out, int out_size, void* d_ws, size_t ws_size,
                              hipStream_t stream) {
    const float* emb   = (const float*)d_in[0];   // [N,128] fp32
    const int*   src   = (const int*)d_in[1];     // [E]
    const int*   dst   = (const int*)d_in[2];     // [E]
    const float* d     = (const float*)d_in[3];   // [128]
    const float* scale = (const float*)d_in[4];   // [1]
    float*       out   = (float*)d_out;           // [E]

    int N = in_sizes[0] / 128;
    int E = in_sizes[1];

    size_t need_fp8 = (size_t)N * 128;            // 12.8 MB
    if (ws_size >= need_fp8) {
        unsigned int* en = (unsigned int*)d_ws;
        {   // 8 rows per 256-thread block (1 row / 32-lane half)
            int blocks = (N + 7) / 8;
            normalize_fp8_kernel<<<blocks, 256, 0, stream>>>(emb, en, N);
        }
        {   // 4 edges per 8-lane group -> 128 edges per 256-thread block
            int groups = (E + 3) / 4;
            long long threads = (long long)groups * 8;
            int blocks = (int)((threads + 255) / 256);
            edge_dot_fp8_v2_kernel<<<blocks, 256, 0, stream>>>(en, src, dst,
                                                               d, scale, out, E);
        }
    } else {
        __half* en = (__half*)d_ws;
        {
            int blocks = (N + 3) / 4;
            normalize_fp16_kernel<<<blocks, 256, 0, stream>>>(emb, en, N);
        }
        {
            int blocks = (E + 15) / 16;
            edge_dot_fp16_kernel<<<blocks, 256, 0, stream>>>(en, src, dst,
                                                             d, scale, out, E);
        }
    }
}